// Round 9
// baseline (152.210 us; speedup 1.0000x reference)
//
#include <hip/hip_runtime.h>

typedef unsigned short u16;
typedef unsigned int u32;
typedef __attribute__((ext_vector_type(8))) __bf16 bf16x8;
typedef __attribute__((ext_vector_type(4))) float f32x4;

// ---- workspace layout (float offsets) ----
constexpr size_t OFF_PI  = 0;                    // pi fp32 [m][64]
constexpr size_t OFF_PBH = 512;                  // P hi bf16 [e][m][c][d] (u16)
constexpr size_t OFF_PBL = OFF_PBH + 1015808;    // P lo
constexpr size_t OFF_NDH = OFF_PBL + 1015808;    // L0 node hi [n(16)][m][b][d] u16
constexpr size_t OFF_NDL = OFF_NDH + 4194304;    // L0 node lo

union FR { uint4 u; bf16x8 v; };

// split x -> hi (RNE bf16) + lo (trunc bf16 of residual)
__device__ __forceinline__ void split_bf16(float x, u16& h, u16& l) {
  u32 b = __float_as_uint(x);
  u32 hb = (b + 0x7fffu + ((b >> 16) & 1u)) & 0xffff0000u;
  h = (u16)(hb >> 16);
  float r = x - __uint_as_float(hb);
  l = (u16)(__float_as_uint(r) >> 16);
}

__device__ __forceinline__ void split8(const f32x4 a, const f32x4 b,
                                       uint4& hi, uint4& lo) {
  u16 h[8], l[8];
  split_bf16(a.x, h[0], l[0]); split_bf16(a.y, h[1], l[1]);
  split_bf16(a.z, h[2], l[2]); split_bf16(a.w, h[3], l[3]);
  split_bf16(b.x, h[4], l[4]); split_bf16(b.y, h[5], l[5]);
  split_bf16(b.z, h[6], l[6]); split_bf16(b.w, h[7], l[7]);
  hi.x = h[0] | ((u32)h[1] << 16); hi.y = h[2] | ((u32)h[3] << 16);
  hi.z = h[4] | ((u32)h[5] << 16); hi.w = h[6] | ((u32)h[7] << 16);
  lo.x = l[0] | ((u32)l[1] << 16); lo.y = l[2] | ((u32)l[3] << 16);
  lo.z = l[4] | ((u32)l[5] << 16); lo.w = l[6] | ((u32)l[7] << 16);
}

__device__ __forceinline__ void mfma3(f32x4& a, const uint4 ah, const uint4 al,
                                      const uint4 bh, const uint4 bl) {
  FR Ah, Al, Bh, Bl;
  Ah.u = ah; Al.u = al; Bh.u = bh; Bl.u = bl;
  a = __builtin_amdgcn_mfma_f32_16x16x32_bf16(Ah.v, Bh.v, a, 0, 0, 0);
  a = __builtin_amdgcn_mfma_f32_16x16x32_bf16(Ah.v, Bl.v, a, 0, 0, 0);
  a = __builtin_amdgcn_mfma_f32_16x16x32_bf16(Al.v, Bh.v, a, 0, 0, 0);
}

// bf16 hi/lo matrix buffer (k_pcomb): 64 rows x 32 dwords hi + 2048 lo; 16B
// chunk j of row r at ((j+r)&7).
__device__ __forceinline__ void xt_read2(const u32* b, int row, int chunk,
                                         uint4& hi, uint4& lo) {
  const int dw = (row << 5) + (((chunk + row) & 7) << 2);
  hi = *(const uint4*)&b[dw];
  lo = *(const uint4*)&b[2048 + dw];
}
__device__ __forceinline__ void xt_write4(u32* b, int row, int cp, int half,
                                          const f32x4 v) {
  u16 h[4], l[4];
  split_bf16(v.x, h[0], l[0]); split_bf16(v.y, h[1], l[1]);
  split_bf16(v.z, h[2], l[2]); split_bf16(v.w, h[3], l[3]);
  const int dw = (row << 5) + (((cp + row) & 7) << 2) + half * 2;
  uint2 hh, ll;
  hh.x = h[0] | ((u32)h[1] << 16); hh.y = h[2] | ((u32)h[3] << 16);
  ll.x = l[0] | ((u32)l[1] << 16); ll.y = l[2] | ((u32)l[3] << 16);
  *(uint2*)&b[dw] = hh;
  *(uint2*)&b[2048 + dw] = ll;
}

// ---------------- K1: pi, Q, squaring ladder, Taylor combine -> P hi/lo -----
// 256 blocks: m = blk&7 (XCD-affine), prt = blk>>3 covers 2 edges. All 12
// power C-frags stay in registers (q[12][4], C-layout); only 5 barriers.
__global__ __launch_bounds__(1024) void k_pcomb(
    const float* __restrict__ R_inv, const float* __restrict__ pi_inv,
    const float* __restrict__ lengths, float* __restrict__ ws,
    u16* __restrict__ PBH, u16* __restrict__ PBL) {
  const int m = blockIdx.x & 7, prt = blockIdx.x >> 3;
  const int tid = threadIdx.x, lane = tid & 63, w = tid >> 6;
  const int ln = lane & 15, kq = lane >> 4;
  const int ct = w >> 2, bt = w & 3;  // one 16x16 tile per wave (16 waves)
  __shared__ float pis[64];
  __shared__ float n2s;
  __shared__ __align__(16) float Qs[64 * 68];
  __shared__ __align__(16) u32 PB[7][4096];  // R0(Q1->Q8),R1(Q2),R2(Q4),C1..C4

  if (tid < 64) {
    float p = (tid < 63) ? pi_inv[m * 63 + tid] : 0.f;
    float v = p * p;
    #pragma unroll
    for (int off = 32; off; off >>= 1) v += __shfl_down(v, off, 64);
    if (tid == 0) n2s = v;
  }
  __syncthreads();
  if (tid < 64) {
    const float den = n2s + 1.f;
    const float x = (tid < 63) ? 2.f * pi_inv[m * 63 + tid] / den
                               : (n2s - 1.f) / den;
    const float pv = x * x;
    pis[tid] = pv;
    if (prt == 0) ws[OFF_PI + (size_t)m * 64 + tid] = pv;
  }
  __syncthreads();
  for (int idx = tid; idx < 4096; idx += 1024) {
    const int i = idx >> 6, j = idx & 63;
    float q = 0.f;
    if (i != j) {
      const int a = min(i, j), b = max(i, j);
      const int kk = a * (127 - a) / 2 + (b - a - 1);
      q = expf(R_inv[m * 2016 + kk]) * pis[j];
    }
    Qs[i * 68 + j] = q;
  }
  __syncthreads();
  if (tid < 64) {
    float s = 0.f;
    #pragma unroll 4
    for (int j4 = 0; j4 < 64; j4 += 4) {
      const f32x4 q = *(const f32x4*)&Qs[tid * 68 + j4];
      s += q.x + q.y + q.z + q.w;
    }
    Qs[tid * 68 + tid] = -s;
  }
  __syncthreads();
  // q[k][r] = (Q^{k+1})[ct*16+kq*4+r][bt*16+ln]  (MFMA C-layout, registers)
  float q[12][4];
  #pragma unroll
  for (int r = 0; r < 4; ++r)
    q[0][r] = Qs[(ct * 16 + kq * 4 + r) * 68 + bt * 16 + ln];
  if (tid < 512) {  // row-layout Q1 -> PB[0]
    const int i = tid >> 3, c = tid & 7;
    const f32x4 a = *(const f32x4*)&Qs[i * 68 + c * 8];
    const f32x4 b = *(const f32x4*)&Qs[i * 68 + c * 8 + 4];
    uint4 h, l;
    split8(a, b, h, l);
    const int dw = (i << 5) + (((c + i) & 7) << 2);
    *(uint4*)&PB[0][dw] = h;
    *(uint4*)&PB[0][2048 + dw] = l;
  } else {  // col-layout Q1 -> PB[3]
    const int t2 = tid - 512, j = t2 >> 3, c = t2 & 7;
    f32x4 a, b;
    a.x = Qs[(c * 8 + 0) * 68 + j]; a.y = Qs[(c * 8 + 1) * 68 + j];
    a.z = Qs[(c * 8 + 2) * 68 + j]; a.w = Qs[(c * 8 + 3) * 68 + j];
    b.x = Qs[(c * 8 + 4) * 68 + j]; b.y = Qs[(c * 8 + 5) * 68 + j];
    b.z = Qs[(c * 8 + 6) * 68 + j]; b.w = Qs[(c * 8 + 7) * 68 + j];
    uint4 h, l;
    split8(a, b, h, l);
    const int dw = (j << 5) + (((c + j) & 7) << 2);
    *(uint4*)&PB[3][dw] = h;
    *(uint4*)&PB[3][2048 + dw] = l;
  }
  __syncthreads();

  const f32x4 z = {0.f, 0.f, 0.f, 0.f};
  auto mmstep = [&](const u32* RX, const u32* CY, float* qk, u32* dstC,
                    u32* dstR) {
    uint4 ah[2], al[2], bh[2], bl[2];
    #pragma unroll
    for (int kh = 0; kh < 2; ++kh) {
      xt_read2(RX, ct * 16 + ln, kh * 4 + kq, ah[kh], al[kh]);
      xt_read2(CY, bt * 16 + ln, kh * 4 + kq, bh[kh], bl[kh]);
    }
    f32x4 a = z;
    #pragma unroll
    for (int kh = 0; kh < 2; ++kh) mfma3(a, ah[kh], al[kh], bh[kh], bl[kh]);
    #pragma unroll
    for (int r = 0; r < 4; ++r) qk[r] = a[r];
    if (dstC) xt_write4(dstC, bt * 16 + ln, 2 * ct + (kq >> 1), kq & 1, a);
    if (dstR) {  // Z^T = Y^T * X^T
      #pragma unroll
      for (int kh = 0; kh < 2; ++kh) {
        xt_read2(CY, ct * 16 + ln, kh * 4 + kq, ah[kh], al[kh]);
        xt_read2(RX, bt * 16 + ln, kh * 4 + kq, bh[kh], bl[kh]);
      }
      f32x4 a2 = z;
      #pragma unroll
      for (int kh = 0; kh < 2; ++kh) mfma3(a2, ah[kh], al[kh], bh[kh], bl[kh]);
      xt_write4(dstR, bt * 16 + ln, 2 * ct + (kq >> 1), kq & 1, a2);
    }
  };
  mmstep(PB[0], PB[3], q[1], PB[4], PB[1]);  __syncthreads();  // Q2
  mmstep(PB[1], PB[3], q[2], PB[5], nullptr); __syncthreads(); // Q3
  mmstep(PB[1], PB[4], q[3], PB[6], PB[2]);  __syncthreads();  // Q4
  mmstep(PB[2], PB[3], q[4], nullptr, nullptr);                // Q5
  mmstep(PB[2], PB[4], q[5], nullptr, nullptr);                // Q6
  mmstep(PB[2], PB[5], q[6], nullptr, nullptr);                // Q7
  mmstep(PB[2], PB[6], q[7], nullptr, PB[0]); __syncthreads(); // Q8 -> rowQ8
  mmstep(PB[0], PB[3], q[8], nullptr, nullptr);                // Q9
  mmstep(PB[0], PB[4], q[9], nullptr, nullptr);                // Q10
  mmstep(PB[0], PB[5], q[10], nullptr, nullptr);               // Q11
  mmstep(PB[0], PB[6], q[11], nullptr, nullptr);               // Q12

  // combine: 2 edges per block, all in registers (C-layout scatter store)
  #pragma unroll
  for (int ei = 0; ei < 2; ++ei) {
    const int e = prt * 2 + ei;
    if (e >= 62) break;
    const float t = lengths[e];
    const int jcol = bt * 16 + ln;
    float av[4];
    #pragma unroll
    for (int r = 0; r < 4; ++r)
      av[r] = (ct * 16 + kq * 4 + r == jcol) ? 1.f : 0.f;
    float cf = 1.f;
    #pragma unroll
    for (int k = 1; k <= 12; ++k) {
      cf *= t / (float)k;
      #pragma unroll
      for (int r = 0; r < 4; ++r) av[r] = fmaf(cf, q[k - 1][r], av[r]);
    }
    const size_t base = (((size_t)e * 8 + m) << 12) + jcol;
    #pragma unroll
    for (int r = 0; r < 4; ++r) {
      u16 h, l;
      split_bf16(av[r], h, l);
      const size_t o = base + (size_t)(ct * 16 + kq * 4 + r) * 64;
      PBH[o] = h;
      PBL[o] = l;
    }
  }
}

// ---------------- K2: level-0, barrier-free streaming ----------------
// 2048 blocks = (m = blk&7 [XCD], pair p, 64-col tile) x 4 waves x 256 thr.
// No LDS, no barriers: leaf+P frags straight from global, MFMA, sibling
// product, write node hi/lo planes. Latency hidden by 8 blocks/CU of TLP.
__global__ __launch_bounds__(256) void k_L0(
    const float* __restrict__ leaves, const u16* __restrict__ Phi,
    const u16* __restrict__ Plo, u16* __restrict__ NDH,
    u16* __restrict__ NDL) {
  const int blk = blockIdx.x;
  const int m = blk & 7, p = (blk >> 3) & 15, jt = blk >> 7;
  const int tid = threadIdx.x, lane = tid & 63, w = tid >> 6;
  const int ln = lane & 15, kq = lane >> 4;
  const int b = jt * 64 + w * 16 + ln;  // batch column
  const f32x4 z = {0.f, 0.f, 0.f, 0.f};
  f32x4 acc0[4], acc1[4];

  #pragma unroll
  for (int s = 0; s < 2; ++s) {
    // leaf B-fragments
    uint4 bh[2], bl[2];
    #pragma unroll
    for (int kh = 0; kh < 2; ++kh) {
      const float* g = leaves + (size_t)b * 2048 + (size_t)(2 * p + s) * 64 +
                       kh * 32 + kq * 8;
      const f32x4 xa = *(const f32x4*)g;
      const f32x4 xb = *(const f32x4*)(g + 4);
      split8(xa, xb, bh[kh], bl[kh]);
    }
    // P fragments + MFMA
    const size_t pb = ((size_t)(2 * p + s) * 8 + m) << 12;
    f32x4* acc = s ? acc1 : acc0;
    #pragma unroll
    for (int ci = 0; ci < 4; ++ci) {
      f32x4 a = z;
      #pragma unroll
      for (int kh = 0; kh < 2; ++kh) {
        const size_t off = pb + (size_t)(ci * 16 + ln) * 64 + kh * 32 + kq * 8;
        const uint4 pah = *(const uint4*)(Phi + off);
        const uint4 pal = *(const uint4*)(Plo + off);
        mfma3(a, pah, pal, bh[kh], bl[kh]);
      }
      acc[ci] = a;
    }
  }
  // sibling product -> node planes [p][m][b][d]
  const size_t nb = (((size_t)p * 8 + m) << 16) + (size_t)b * 64;
  #pragma unroll
  for (int ci = 0; ci < 4; ++ci) {
    const f32x4 pr = acc0[ci] * acc1[ci];
    u16 h[4], l[4];
    split_bf16(pr.x, h[0], l[0]); split_bf16(pr.y, h[1], l[1]);
    split_bf16(pr.z, h[2], l[2]); split_bf16(pr.w, h[3], l[3]);
    ushort4 h4, l4;
    h4.x = h[0]; h4.y = h[1]; h4.z = h[2]; h4.w = h[3];
    l4.x = l[0]; l4.y = l[1]; l4.z = l[2]; l4.w = l[3];
    const size_t o = nb + ci * 16 + kq * 4;
    *(ushort4*)(NDH + o) = h4;
    *(ushort4*)(NDL + o) = l4;
  }
}

// ---------------- K3: upper tree (levels 1-4) + final dot ----------------
// 512 blocks = (m = blk&7, 16-col tile) x 8 waves. L0 nodes read from global
// (L2-hot); intermediates in 12 LDS slots x 4 KB = 48 KB -> 2-3 blocks/CU.
// Slots: L1 out -> w (0..7); L2 pair j reads (2j,2j+1) -> 8+j; L3 pair j
// reads (8+2j, 8+2j+1) -> j (0..7 dead after L2); L4 reads (0,1).
__global__ __launch_bounds__(512) void k_upper(
    const u16* __restrict__ NDH, const u16* __restrict__ NDL,
    const u16* __restrict__ Phi, const u16* __restrict__ Plo,
    const float* __restrict__ ws, float* __restrict__ out) {
  const int m = blockIdx.x & 7, jt = blockIdx.x >> 3;
  const int tid = threadIdx.x, lane = tid & 63, w = tid >> 6;
  const int ln = lane & 15, kq = lane >> 4;
  __shared__ __align__(16) u32 slots[12 * 1024];  // 48 KB
  __shared__ float psum[4][16];
  const f32x4 z = {0.f, 0.f, 0.f, 0.f};

  // interleaved h|l node chunk helpers (16 rows x 64 dwords per slot)
  auto node_read = [&](int slot, int row, int kh, uint4& bh, uint4& bl) {
    const int jc = kh * 8 + kq * 2;
    const u32* nb = &slots[slot * 1024 + row * 64];
    const uint4 A = *(const uint4*)&nb[((jc + row) & 15) << 2];
    const uint4 B = *(const uint4*)&nb[((jc + 1 + row) & 15) << 2];
    bh.x = A.x; bh.y = A.y; bh.z = B.x; bh.w = B.y;
    bl.x = A.z; bl.y = A.w; bl.z = B.z; bl.w = B.w;
  };
  auto node_write = [&](int slot, int row, int jc, const f32x4 v) {
    u16 h[4], l[4];
    split_bf16(v.x, h[0], l[0]); split_bf16(v.y, h[1], l[1]);
    split_bf16(v.z, h[2], l[2]); split_bf16(v.w, h[3], l[3]);
    uint4 pk;
    pk.x = h[0] | ((u32)h[1] << 16); pk.y = h[2] | ((u32)h[3] << 16);
    pk.z = l[0] | ((u32)l[1] << 16); pk.w = l[2] | ((u32)l[3] << 16);
    *(uint4*)&slots[slot * 1024 + row * 64 + (((jc + row) & 15) << 2)] = pk;
  };

  // generic pair: B from global planes (lvl1) or LDS slots; ct range [ct0,ct0+nct)
  auto do_pair = [&](int e0, int g0, int s0, int s1, int outSlot, int ct0,
                     int nct, bool fromGlobal, f32x4* rootout) {
    uint4 bh[2][2], bl[2][2];  // [sib][kh]
    #pragma unroll
    for (int s = 0; s < 2; ++s)
      #pragma unroll
      for (int kh = 0; kh < 2; ++kh) {
        if (fromGlobal) {
          const size_t nb =
              (((size_t)(g0 + s) * 8 + m) << 16) + (size_t)(jt * 16 + ln) * 64;
          bh[s][kh] = *(const uint4*)(NDH + nb + kh * 32 + kq * 8);
          bl[s][kh] = *(const uint4*)(NDL + nb + kh * 32 + kq * 8);
        } else {
          node_read(s ? s1 : s0, ln, kh, bh[s][kh], bl[s][kh]);
        }
      }
    f32x4 acc0[4];
    #pragma unroll
    for (int s = 0; s < 2; ++s) {
      const size_t pb = ((size_t)(e0 + s) * 8 + m) << 12;
      #pragma unroll
      for (int ci = 0; ci < 4; ++ci) {
        if (ci >= nct) continue;
        uint4 pah[2], pal[2];
        #pragma unroll
        for (int kh = 0; kh < 2; ++kh) {
          const size_t off =
              pb + (size_t)((ct0 + ci) * 16 + ln) * 64 + kh * 32 + kq * 8;
          pah[kh] = *(const uint4*)(Phi + off);
          pal[kh] = *(const uint4*)(Plo + off);
        }
        f32x4 a = z;
        #pragma unroll
        for (int kh = 0; kh < 2; ++kh)
          mfma3(a, pah[kh], pal[kh], bh[s][kh], bl[s][kh]);
        if (s == 0) {
          acc0[ci] = a;
        } else {
          const f32x4 pr = acc0[ci] * a;
          if (rootout) {
            rootout[ci] = pr;
          } else {
            node_write(outSlot, ln, (ct0 + ci) * 4 + kq, pr);
          }
        }
      }
    }
  };

  // L1: 8 pairs, pair-per-wave; global nodes (2w, 2w+1) -> slot w
  do_pair(32 + 2 * w, 2 * w, -1, -1, w, 0, 4, true, nullptr);
  __syncthreads();
  // L2: 4 pairs x 2 ct-waves: slots (2j, 2j+1) -> 8+j
  {
    const int j = w >> 1, ch = (w & 1) * 2;
    do_pair(48 + 2 * j, 0, 2 * j, 2 * j + 1, 8 + j, ch, 2, false, nullptr);
  }
  __syncthreads();
  // L3: 2 pairs x 2 ct-waves (waves 0-3): slots (8+2j, 8+2j+1) -> j
  if (w < 4) {
    const int j = w >> 1, ch = (w & 1) * 2;
    do_pair(56 + 2 * j, 0, 8 + 2 * j, 8 + 2 * j + 1, j, ch, 2, false, nullptr);
  }
  __syncthreads();
  // L4: 1 pair x 2 ct-waves (waves 0-1): slots (0,1); fused dot with pi
  if (w < 2) {
    f32x4 root[4];
    const int ch = w * 2;
    do_pair(60, 0, 0, 1, -1, ch, 2, false, root);
    #pragma unroll
    for (int ci = 0; ci < 2; ++ci) {
      const int ct = ch + ci;
      const f32x4 piv =
          *(const f32x4*)&ws[OFF_PI + (size_t)m * 64 + ct * 16 + kq * 4];
      const f32x4 pr = root[ci];
      float v = pr.x * piv.x + pr.y * piv.y + pr.z * piv.z + pr.w * piv.w;
      v += __shfl_xor(v, 16, 64);
      v += __shfl_xor(v, 32, 64);
      if (lane < 16) psum[ct][lane] = v;
    }
  }
  __syncthreads();
  if (tid < 16)
    out[(size_t)(jt * 16 + tid) * 8 + m] =
        psum[0][tid] + psum[1][tid] + psum[2][tid] + psum[3][tid];
}

extern "C" void kernel_launch(void* const* d_in, const int* in_sizes, int n_in,
                              void* d_out, int out_size, void* d_ws, size_t ws_size,
                              hipStream_t stream) {
  const float* leaves  = (const float*)d_in[0];  // (B, 32, 64)
  const float* R_inv   = (const float*)d_in[1];  // (8, 2016)
  const float* pi_inv  = (const float*)d_in[2];  // (8, 63)
  const float* lengths = (const float*)d_in[3];  // (62,)
  float* out = (float*)d_out;                    // (B, 8)
  float* ws  = (float*)d_ws;

  u16* PBH = (u16*)(ws + OFF_PBH);
  u16* PBL = (u16*)(ws + OFF_PBL);
  u16* NDH = (u16*)(ws + OFF_NDH);
  u16* NDL = (u16*)(ws + OFF_NDL);

  hipLaunchKernelGGL(k_pcomb, dim3(256), dim3(1024), 0, stream, R_inv, pi_inv,
                     lengths, ws, PBH, PBL);
  hipLaunchKernelGGL(k_L0, dim3(2048), dim3(256), 0, stream, leaves, PBH, PBL,
                     NDH, NDL);
  hipLaunchKernelGGL(k_upper, dim3(512), dim3(512), 0, stream, NDH, NDL, PBH,
                     PBL, ws, out);
}

// Round 10
// 135.609 us; speedup vs baseline: 1.1224x; 1.1224x over previous
//
#include <hip/hip_runtime.h>

typedef unsigned short u16;
typedef unsigned int u32;
typedef __attribute__((ext_vector_type(8))) __bf16 bf16x8;
typedef __attribute__((ext_vector_type(4))) float f32x4;

// ---- workspace layout (float offsets) ----
constexpr size_t OFF_PI  = 0;                      // pi fp32 [m][64]
constexpr size_t OFF_PBH = 512;                    // P hi bf16 [e][m][c][d]
constexpr size_t OFF_PBL = OFF_PBH + 1015808;      // P lo
constexpr size_t OFF_LFH = OFF_PBL + 1015808;      // leaf planes hi [leaf][b][d]
constexpr size_t OFF_LFL = OFF_LFH + 1048576;
constexpr size_t OFF_N0H = OFF_LFL + 1048576;      // L0 nodes hi [n16][m][b][c]
constexpr size_t OFF_N0L = OFF_N0H + 4194304;
constexpr size_t OFF_N2H = OFF_N0L + 4194304;      // L2 nodes hi [n4][m][b][c]
constexpr size_t OFF_N2L = OFF_N2H + 1048576;

union FR { uint4 u; bf16x8 v; };

__device__ __forceinline__ void split_bf16(float x, u16& h, u16& l) {
  u32 b = __float_as_uint(x);
  u32 hb = (b + 0x7fffu + ((b >> 16) & 1u)) & 0xffff0000u;
  h = (u16)(hb >> 16);
  float r = x - __uint_as_float(hb);
  l = (u16)(__float_as_uint(r) >> 16);
}

__device__ __forceinline__ void split8(const f32x4 a, const f32x4 b,
                                       uint4& hi, uint4& lo) {
  u16 h[8], l[8];
  split_bf16(a.x, h[0], l[0]); split_bf16(a.y, h[1], l[1]);
  split_bf16(a.z, h[2], l[2]); split_bf16(a.w, h[3], l[3]);
  split_bf16(b.x, h[4], l[4]); split_bf16(b.y, h[5], l[5]);
  split_bf16(b.z, h[6], l[6]); split_bf16(b.w, h[7], l[7]);
  hi.x = h[0] | ((u32)h[1] << 16); hi.y = h[2] | ((u32)h[3] << 16);
  hi.z = h[4] | ((u32)h[5] << 16); hi.w = h[6] | ((u32)h[7] << 16);
  lo.x = l[0] | ((u32)l[1] << 16); lo.y = l[2] | ((u32)l[3] << 16);
  lo.z = l[4] | ((u32)l[5] << 16); lo.w = l[6] | ((u32)l[7] << 16);
}

// product f32x4 -> interleaved {h01,h23,l01,l23} chunk
__device__ __forceinline__ uint4 pack_hl(const f32x4 v) {
  u16 h[4], l[4];
  split_bf16(v.x, h[0], l[0]); split_bf16(v.y, h[1], l[1]);
  split_bf16(v.z, h[2], l[2]); split_bf16(v.w, h[3], l[3]);
  uint4 pk;
  pk.x = h[0] | ((u32)h[1] << 16); pk.y = h[2] | ((u32)h[3] << 16);
  pk.z = l[0] | ((u32)l[1] << 16); pk.w = l[2] | ((u32)l[3] << 16);
  return pk;
}
__device__ __forceinline__ void split4s(const f32x4 v, ushort4& h4, ushort4& l4) {
  split_bf16(v.x, h4.x, l4.x); split_bf16(v.y, h4.y, l4.y);
  split_bf16(v.z, h4.z, l4.z); split_bf16(v.w, h4.w, l4.w);
}

__device__ __forceinline__ void mfma3(f32x4& a, const uint4 ah, const uint4 al,
                                      const uint4 bh, const uint4 bl) {
  FR Ah, Al, Bh, Bl;
  Ah.u = ah; Al.u = al; Bh.u = bh; Bl.u = bl;
  a = __builtin_amdgcn_mfma_f32_16x16x32_bf16(Ah.v, Bh.v, a, 0, 0, 0);
  a = __builtin_amdgcn_mfma_f32_16x16x32_bf16(Ah.v, Bl.v, a, 0, 0, 0);
  a = __builtin_amdgcn_mfma_f32_16x16x32_bf16(Al.v, Bh.v, a, 0, 0, 0);
}

// bf16 hi/lo matrix buffer (k_pcomb ladder): 64 rows x (32 hi + 32 lo) dwords
__device__ __forceinline__ void xt_read2(const u32* b, int row, int chunk,
                                         uint4& hi, uint4& lo) {
  const int dw = (row << 5) + (((chunk + row) & 7) << 2);
  hi = *(const uint4*)&b[dw];
  lo = *(const uint4*)&b[2048 + dw];
}
__device__ __forceinline__ void xt_write4(u32* b, int row, int cp, int half,
                                          const f32x4 v) {
  u16 h[4], l[4];
  split_bf16(v.x, h[0], l[0]); split_bf16(v.y, h[1], l[1]);
  split_bf16(v.z, h[2], l[2]); split_bf16(v.w, h[3], l[3]);
  const int dw = (row << 5) + (((cp + row) & 7) << 2) + half * 2;
  uint2 hh, ll;
  hh.x = h[0] | ((u32)h[1] << 16); hh.y = h[2] | ((u32)h[3] << 16);
  ll.x = l[0] | ((u32)l[1] << 16); ll.y = l[2] | ((u32)l[3] << 16);
  *(uint2*)&b[dw] = hh;
  *(uint2*)&b[2048 + dw] = ll;
}

// ---------------- K1: pi, Q, ladder, combine -> P hi/lo; tail: leaf split ----
__global__ __launch_bounds__(1024) void k_pcomb(
    const float* __restrict__ R_inv, const float* __restrict__ pi_inv,
    const float* __restrict__ lengths, const float* __restrict__ leaves,
    float* __restrict__ ws, u16* __restrict__ PBH, u16* __restrict__ PBL,
    u16* __restrict__ LFH, u16* __restrict__ LFL) {
  const int m = blockIdx.x & 7, prt = blockIdx.x >> 3;
  const int tid = threadIdx.x, lane = tid & 63, w = tid >> 6;
  const int ln = lane & 15, kq = lane >> 4;
  const int ct = w >> 2, bt = w & 3;
  __shared__ float pis[64];
  __shared__ float n2s;
  __shared__ __align__(16) float Qs[64 * 68];
  __shared__ __align__(16) u32 PB[7][4096];  // R0(Q1->Q8),R1(Q2),R2(Q4),C1..C4

  if (tid < 64) {
    float p = (tid < 63) ? pi_inv[m * 63 + tid] : 0.f;
    float v = p * p;
    #pragma unroll
    for (int off = 32; off; off >>= 1) v += __shfl_down(v, off, 64);
    if (tid == 0) n2s = v;
  }
  __syncthreads();
  if (tid < 64) {
    const float den = n2s + 1.f;
    const float x = (tid < 63) ? 2.f * pi_inv[m * 63 + tid] / den
                               : (n2s - 1.f) / den;
    const float pv = x * x;
    pis[tid] = pv;
    if (prt == 0) ws[OFF_PI + (size_t)m * 64 + tid] = pv;
  }
  __syncthreads();
  for (int idx = tid; idx < 4096; idx += 1024) {
    const int i = idx >> 6, j = idx & 63;
    float q = 0.f;
    if (i != j) {
      const int a = min(i, j), b = max(i, j);
      const int kk = a * (127 - a) / 2 + (b - a - 1);
      q = expf(R_inv[m * 2016 + kk]) * pis[j];
    }
    Qs[i * 68 + j] = q;
  }
  __syncthreads();
  if (tid < 64) {
    float s = 0.f;
    #pragma unroll 4
    for (int j4 = 0; j4 < 64; j4 += 4) {
      const f32x4 q = *(const f32x4*)&Qs[tid * 68 + j4];
      s += q.x + q.y + q.z + q.w;
    }
    Qs[tid * 68 + tid] = -s;
  }
  __syncthreads();
  float q[12][4];
  #pragma unroll
  for (int r = 0; r < 4; ++r)
    q[0][r] = Qs[(ct * 16 + kq * 4 + r) * 68 + bt * 16 + ln];
  if (tid < 512) {
    const int i = tid >> 3, c = tid & 7;
    const f32x4 a = *(const f32x4*)&Qs[i * 68 + c * 8];
    const f32x4 b = *(const f32x4*)&Qs[i * 68 + c * 8 + 4];
    uint4 h, l;
    split8(a, b, h, l);
    const int dw = (i << 5) + (((c + i) & 7) << 2);
    *(uint4*)&PB[0][dw] = h;
    *(uint4*)&PB[0][2048 + dw] = l;
  } else {
    const int t2 = tid - 512, j = t2 >> 3, c = t2 & 7;
    f32x4 a, b;
    a.x = Qs[(c * 8 + 0) * 68 + j]; a.y = Qs[(c * 8 + 1) * 68 + j];
    a.z = Qs[(c * 8 + 2) * 68 + j]; a.w = Qs[(c * 8 + 3) * 68 + j];
    b.x = Qs[(c * 8 + 4) * 68 + j]; b.y = Qs[(c * 8 + 5) * 68 + j];
    b.z = Qs[(c * 8 + 6) * 68 + j]; b.w = Qs[(c * 8 + 7) * 68 + j];
    uint4 h, l;
    split8(a, b, h, l);
    const int dw = (j << 5) + (((c + j) & 7) << 2);
    *(uint4*)&PB[3][dw] = h;
    *(uint4*)&PB[3][2048 + dw] = l;
  }
  __syncthreads();

  const f32x4 z = {0.f, 0.f, 0.f, 0.f};
  auto mmstep = [&](const u32* RX, const u32* CY, float* qk, u32* dstC,
                    u32* dstR) {
    uint4 ah[2], al[2], bh[2], bl[2];
    #pragma unroll
    for (int kh = 0; kh < 2; ++kh) {
      xt_read2(RX, ct * 16 + ln, kh * 4 + kq, ah[kh], al[kh]);
      xt_read2(CY, bt * 16 + ln, kh * 4 + kq, bh[kh], bl[kh]);
    }
    f32x4 a = z;
    #pragma unroll
    for (int kh = 0; kh < 2; ++kh) mfma3(a, ah[kh], al[kh], bh[kh], bl[kh]);
    #pragma unroll
    for (int r = 0; r < 4; ++r) qk[r] = a[r];
    if (dstC) xt_write4(dstC, bt * 16 + ln, 2 * ct + (kq >> 1), kq & 1, a);
    if (dstR) {
      #pragma unroll
      for (int kh = 0; kh < 2; ++kh) {
        xt_read2(CY, ct * 16 + ln, kh * 4 + kq, ah[kh], al[kh]);
        xt_read2(RX, bt * 16 + ln, kh * 4 + kq, bh[kh], bl[kh]);
      }
      f32x4 a2 = z;
      #pragma unroll
      for (int kh = 0; kh < 2; ++kh) mfma3(a2, ah[kh], al[kh], bh[kh], bl[kh]);
      xt_write4(dstR, bt * 16 + ln, 2 * ct + (kq >> 1), kq & 1, a2);
    }
  };
  mmstep(PB[0], PB[3], q[1], PB[4], PB[1]);  __syncthreads();
  mmstep(PB[1], PB[3], q[2], PB[5], nullptr); __syncthreads();
  mmstep(PB[1], PB[4], q[3], PB[6], PB[2]);  __syncthreads();
  mmstep(PB[2], PB[3], q[4], nullptr, nullptr);
  mmstep(PB[2], PB[4], q[5], nullptr, nullptr);
  mmstep(PB[2], PB[5], q[6], nullptr, nullptr);
  mmstep(PB[2], PB[6], q[7], nullptr, PB[0]); __syncthreads();
  mmstep(PB[0], PB[3], q[8], nullptr, nullptr);
  mmstep(PB[0], PB[4], q[9], nullptr, nullptr);
  mmstep(PB[0], PB[5], q[10], nullptr, nullptr);
  mmstep(PB[0], PB[6], q[11], nullptr, nullptr);

  #pragma unroll
  for (int ei = 0; ei < 2; ++ei) {
    const int e = prt * 2 + ei;
    if (e >= 62) break;
    const float t = lengths[e];
    const int jcol = bt * 16 + ln;
    float av[4];
    #pragma unroll
    for (int r = 0; r < 4; ++r)
      av[r] = (ct * 16 + kq * 4 + r == jcol) ? 1.f : 0.f;
    float cf = 1.f;
    #pragma unroll
    for (int k = 1; k <= 12; ++k) {
      cf *= t / (float)k;
      #pragma unroll
      for (int r = 0; r < 4; ++r) av[r] = fmaf(cf, q[k - 1][r], av[r]);
    }
    const size_t base = (((size_t)e * 8 + m) << 12) + jcol;
    #pragma unroll
    for (int r = 0; r < 4; ++r) {
      u16 h, l;
      split_bf16(av[r], h, l);
      const size_t o = base + (size_t)(ct * 16 + kq * 4 + r) * 64;
      PBH[o] = h;
      PBL[o] = l;
    }
  }

  // tail: pre-split this block's 8192-float leaf chunk into hi/lo planes
  #pragma unroll
  for (int it = 0; it < 2; ++it) {
    const size_t f = (size_t)blockIdx.x * 8192 + it * 4096 + tid * 4;
    const int b = (int)(f >> 11), leaf = (int)((f >> 6) & 31), d = (int)(f & 63);
    const f32x4 v = *(const f32x4*)(leaves + f);
    ushort4 h4, l4;
    split4s(v, h4, l4);
    const size_t o = (((size_t)leaf * 1024 + b) << 6) + d;
    *(ushort4*)(LFH + o) = h4;
    *(ushort4*)(LFL + o) = l4;
  }
}

// ---------------- K2: level 0 — P register-resident streaming GEMM ----------
// 512 blocks = (m=blk&7, p=(blk>>3)&15, bq=blk>>7) x 4 waves; wave holds the
// full 2-sibling P (32 uint4) and loops 4 independent 16-row tiles.
__global__ __launch_bounds__(256, 2) void k_L0(
    const u16* __restrict__ LFH, const u16* __restrict__ LFL,
    const u16* __restrict__ Phi, const u16* __restrict__ Plo,
    u16* __restrict__ N0H, u16* __restrict__ N0L) {
  const int blk = blockIdx.x;
  const int m = blk & 7, p = (blk >> 3) & 15, bq = blk >> 7;
  const int tid = threadIdx.x, lane = tid & 63, w = tid >> 6;
  const int ln = lane & 15, kq = lane >> 4;
  const f32x4 z = {0.f, 0.f, 0.f, 0.f};

  uint4 ph[2][4][2], pl[2][4][2];
  #pragma unroll
  for (int s = 0; s < 2; ++s) {
    const size_t pb = ((size_t)(2 * p + s) * 8 + m) << 12;
    #pragma unroll
    for (int ci = 0; ci < 4; ++ci)
      #pragma unroll
      for (int kh = 0; kh < 2; ++kh) {
        const size_t off = pb + (size_t)(ci * 16 + ln) * 64 + kh * 32 + kq * 8;
        ph[s][ci][kh] = *(const uint4*)(Phi + off);
        pl[s][ci][kh] = *(const uint4*)(Plo + off);
      }
  }
  const size_t nbase = (((size_t)p * 8 + m) << 16);
  #pragma unroll
  for (int ti = 0; ti < 4; ++ti) {
    const int b = bq * 256 + w * 64 + ti * 16 + ln;
    uint4 bh[2][2], bl[2][2];
    #pragma unroll
    for (int s = 0; s < 2; ++s)
      #pragma unroll
      for (int kh = 0; kh < 2; ++kh) {
        const size_t o =
            (((size_t)(2 * p + s) * 1024 + b) << 6) + kh * 32 + kq * 8;
        bh[s][kh] = *(const uint4*)(LFH + o);
        bl[s][kh] = *(const uint4*)(LFL + o);
      }
    #pragma unroll
    for (int ci = 0; ci < 4; ++ci) {
      f32x4 a0 = z, a1 = z;
      #pragma unroll
      for (int kh = 0; kh < 2; ++kh) {
        mfma3(a0, ph[0][ci][kh], pl[0][ci][kh], bh[0][kh], bl[0][kh]);
        mfma3(a1, ph[1][ci][kh], pl[1][ci][kh], bh[1][kh], bl[1][kh]);
      }
      const f32x4 pr = a0 * a1;
      ushort4 h4, l4;
      split4s(pr, h4, l4);
      const size_t o = nbase + ((size_t)b << 6) + ci * 16 + kq * 4;
      *(ushort4*)(N0H + o) = h4;
      *(ushort4*)(N0L + o) = l4;
    }
  }
}

// ---------------- K3: levels 1+2, one barrier ----------------
// 256 blocks = (m=blk&7, j=(blk>>3)&3, bq=blk>>5 of 128 cols) x 8 waves.
// L1 outs in LDS (2 slots x 128 rows, interleaved h|l chunks, XOR swizzle);
// L2 outs -> global N2 planes.
__global__ __launch_bounds__(512) void k_L12(
    const u16* __restrict__ N0H, const u16* __restrict__ N0L,
    const u16* __restrict__ Phi, const u16* __restrict__ Plo,
    u16* __restrict__ N2H, u16* __restrict__ N2L) {
  const int m = blockIdx.x & 7, j = (blockIdx.x >> 3) & 3, bq = blockIdx.x >> 5;
  const int tid = threadIdx.x, lane = tid & 63, w = tid >> 6;
  const int ln = lane & 15, kq = lane >> 4;
  __shared__ __align__(16) u32 slots[2][128 * 64];  // 64 KB
  const f32x4 z = {0.f, 0.f, 0.f, 0.f};

  {  // L1: wave = (ps = w&1, ct = w>>1); pair 2j+ps, edges 32+2*(2j+ps)+s
    const int ps = w & 1, ct = w >> 1;
    const int pairg = 2 * j + ps;
    uint4 ph[2][2], pl[2][2];
    #pragma unroll
    for (int s = 0; s < 2; ++s) {
      const size_t pb = ((size_t)(32 + 2 * pairg + s) * 8 + m) << 12;
      #pragma unroll
      for (int kh = 0; kh < 2; ++kh) {
        const size_t off = pb + (size_t)(ct * 16 + ln) * 64 + kh * 32 + kq * 8;
        ph[s][kh] = *(const uint4*)(Phi + off);
        pl[s][kh] = *(const uint4*)(Plo + off);
      }
    }
    for (int ti = 0; ti < 8; ++ti) {
      const int lr = ti * 16 + ln;
      const int b = bq * 128 + lr;
      uint4 bh[2][2], bl[2][2];
      #pragma unroll
      for (int s = 0; s < 2; ++s) {
        const int n = 2 * pairg + s;
        #pragma unroll
        for (int kh = 0; kh < 2; ++kh) {
          const size_t o =
              ((((size_t)n * 8 + m) * 1024 + b) << 6) + kh * 32 + kq * 8;
          bh[s][kh] = *(const uint4*)(N0H + o);
          bl[s][kh] = *(const uint4*)(N0L + o);
        }
      }
      f32x4 a0 = z, a1 = z;
      #pragma unroll
      for (int kh = 0; kh < 2; ++kh) {
        mfma3(a0, ph[0][kh], pl[0][kh], bh[0][kh], bl[0][kh]);
        mfma3(a1, ph[1][kh], pl[1][kh], bh[1][kh], bl[1][kh]);
      }
      const uint4 pk = pack_hl(a0 * a1);
      const int jc = ct * 4 + kq;
      slots[ps][lr * 64 + (((jc + lr) & 15) << 2)] = pk.x;
      *(uint4*)&slots[ps][lr * 64 + (((jc + lr) & 15) << 2)] = pk;
    }
  }
  __syncthreads();
  {  // L2: wave = (ct = w&3, bh2 = w>>2); pair j, edges 48+2j+s
    const int ct = w & 3, bh2 = w >> 2;
    uint4 ph[2][2], pl[2][2];
    #pragma unroll
    for (int s = 0; s < 2; ++s) {
      const size_t pb = ((size_t)(48 + 2 * j + s) * 8 + m) << 12;
      #pragma unroll
      for (int kh = 0; kh < 2; ++kh) {
        const size_t off = pb + (size_t)(ct * 16 + ln) * 64 + kh * 32 + kq * 8;
        ph[s][kh] = *(const uint4*)(Phi + off);
        pl[s][kh] = *(const uint4*)(Plo + off);
      }
    }
    for (int ti = 0; ti < 4; ++ti) {
      const int lr = bh2 * 64 + ti * 16 + ln;
      const int b = bq * 128 + lr;
      uint4 bh[2][2], bl[2][2];
      #pragma unroll
      for (int s = 0; s < 2; ++s)
        #pragma unroll
        for (int kh = 0; kh < 2; ++kh) {
          const int jc = kh * 8 + kq * 2;
          const u32* nb = &slots[s][lr * 64];
          const uint4 A = *(const uint4*)&nb[((jc + lr) & 15) << 2];
          const uint4 B = *(const uint4*)&nb[((jc + 1 + lr) & 15) << 2];
          bh[s][kh].x = A.x; bh[s][kh].y = A.y;
          bh[s][kh].z = B.x; bh[s][kh].w = B.y;
          bl[s][kh].x = A.z; bl[s][kh].y = A.w;
          bl[s][kh].z = B.z; bl[s][kh].w = B.w;
        }
      f32x4 a0 = z, a1 = z;
      #pragma unroll
      for (int kh = 0; kh < 2; ++kh) {
        mfma3(a0, ph[0][kh], pl[0][kh], bh[0][kh], bl[0][kh]);
        mfma3(a1, ph[1][kh], pl[1][kh], bh[1][kh], bl[1][kh]);
      }
      const f32x4 pr = a0 * a1;
      ushort4 h4, l4;
      split4s(pr, h4, l4);
      const size_t o = ((((size_t)j * 8 + m) * 1024 + b) << 6) + ct * 16 + kq * 4;
      *(ushort4*)(N2H + o) = h4;
      *(ushort4*)(N2L + o) = l4;
    }
  }
}

// ---------------- K4: levels 3+4 + pi-dot, one barrier ----------------
// 128 blocks = (m=blk&7, bq=blk>>3 of 64 cols) x 8 waves.
__global__ __launch_bounds__(512) void k_L34(
    const u16* __restrict__ N2H, const u16* __restrict__ N2L,
    const u16* __restrict__ Phi, const u16* __restrict__ Plo,
    const float* __restrict__ ws, float* __restrict__ out) {
  const int m = blockIdx.x & 7, bq = blockIdx.x >> 3;
  const int tid = threadIdx.x, lane = tid & 63, w = tid >> 6;
  const int ln = lane & 15, kq = lane >> 4;
  __shared__ __align__(16) u32 slots[2][64 * 64];  // 32 KB
  __shared__ float psum2[64][4];
  const f32x4 z = {0.f, 0.f, 0.f, 0.f};

  {  // L3: wave = (ps = w&1, ct = w>>1); edges 56+2ps+s, inputs N2 nodes 2ps+s
    const int ps = w & 1, ct = w >> 1;
    uint4 ph[2][2], pl[2][2];
    #pragma unroll
    for (int s = 0; s < 2; ++s) {
      const size_t pb = ((size_t)(56 + 2 * ps + s) * 8 + m) << 12;
      #pragma unroll
      for (int kh = 0; kh < 2; ++kh) {
        const size_t off = pb + (size_t)(ct * 16 + ln) * 64 + kh * 32 + kq * 8;
        ph[s][kh] = *(const uint4*)(Phi + off);
        pl[s][kh] = *(const uint4*)(Plo + off);
      }
    }
    for (int ti = 0; ti < 4; ++ti) {
      const int lr = ti * 16 + ln;
      const int b = bq * 64 + lr;
      uint4 bh[2][2], bl[2][2];
      #pragma unroll
      for (int s = 0; s < 2; ++s) {
        const int n = 2 * ps + s;
        #pragma unroll
        for (int kh = 0; kh < 2; ++kh) {
          const size_t o =
              ((((size_t)n * 8 + m) * 1024 + b) << 6) + kh * 32 + kq * 8;
          bh[s][kh] = *(const uint4*)(N2H + o);
          bl[s][kh] = *(const uint4*)(N2L + o);
        }
      }
      f32x4 a0 = z, a1 = z;
      #pragma unroll
      for (int kh = 0; kh < 2; ++kh) {
        mfma3(a0, ph[0][kh], pl[0][kh], bh[0][kh], bl[0][kh]);
        mfma3(a1, ph[1][kh], pl[1][kh], bh[1][kh], bl[1][kh]);
      }
      const uint4 pk = pack_hl(a0 * a1);
      const int jc = ct * 4 + kq;
      *(uint4*)&slots[ps][lr * 64 + (((jc + lr) & 15) << 2)] = pk;
    }
  }
  __syncthreads();
  {  // L4: wave = (ct = w&3, bh2 = w>>2); edges 60+s, inputs slots 0,1
    const int ct = w & 3, bh2 = w >> 2;
    uint4 ph[2][2], pl[2][2];
    #pragma unroll
    for (int s = 0; s < 2; ++s) {
      const size_t pb = ((size_t)(60 + s) * 8 + m) << 12;
      #pragma unroll
      for (int kh = 0; kh < 2; ++kh) {
        const size_t off = pb + (size_t)(ct * 16 + ln) * 64 + kh * 32 + kq * 8;
        ph[s][kh] = *(const uint4*)(Phi + off);
        pl[s][kh] = *(const uint4*)(Plo + off);
      }
    }
    const f32x4 piv =
        *(const f32x4*)&ws[OFF_PI + (size_t)m * 64 + ct * 16 + kq * 4];
    for (int ti = 0; ti < 2; ++ti) {
      const int lr = bh2 * 32 + ti * 16 + ln;
      uint4 bh[2][2], bl[2][2];
      #pragma unroll
      for (int s = 0; s < 2; ++s)
        #pragma unroll
        for (int kh = 0; kh < 2; ++kh) {
          const int jc = kh * 8 + kq * 2;
          const u32* nb = &slots[s][lr * 64];
          const uint4 A = *(const uint4*)&nb[((jc + lr) & 15) << 2];
          const uint4 B = *(const uint4*)&nb[((jc + 1 + lr) & 15) << 2];
          bh[s][kh].x = A.x; bh[s][kh].y = A.y;
          bh[s][kh].z = B.x; bh[s][kh].w = B.y;
          bl[s][kh].x = A.z; bl[s][kh].y = A.w;
          bl[s][kh].z = B.z; bl[s][kh].w = B.w;
        }
      f32x4 a0 = z, a1 = z;
      #pragma unroll
      for (int kh = 0; kh < 2; ++kh) {
        mfma3(a0, ph[0][kh], pl[0][kh], bh[0][kh], bl[0][kh]);
        mfma3(a1, ph[1][kh], pl[1][kh], bh[1][kh], bl[1][kh]);
      }
      const f32x4 pr = a0 * a1;
      float v = pr.x * piv.x + pr.y * piv.y + pr.z * piv.z + pr.w * piv.w;
      v += __shfl_xor(v, 16, 64);
      v += __shfl_xor(v, 32, 64);
      if (lane < 16) psum2[lr][ct] = v;
    }
  }
  __syncthreads();
  if (tid < 64)
    out[(size_t)(bq * 64 + tid) * 8 + m] =
        psum2[tid][0] + psum2[tid][1] + psum2[tid][2] + psum2[tid][3];
}

extern "C" void kernel_launch(void* const* d_in, const int* in_sizes, int n_in,
                              void* d_out, int out_size, void* d_ws, size_t ws_size,
                              hipStream_t stream) {
  const float* leaves  = (const float*)d_in[0];  // (B, 32, 64)
  const float* R_inv   = (const float*)d_in[1];  // (8, 2016)
  const float* pi_inv  = (const float*)d_in[2];  // (8, 63)
  const float* lengths = (const float*)d_in[3];  // (62,)
  float* out = (float*)d_out;                    // (B, 8)
  float* ws  = (float*)d_ws;

  u16* PBH = (u16*)(ws + OFF_PBH);
  u16* PBL = (u16*)(ws + OFF_PBL);
  u16* LFH = (u16*)(ws + OFF_LFH);
  u16* LFL = (u16*)(ws + OFF_LFL);
  u16* N0H = (u16*)(ws + OFF_N0H);
  u16* N0L = (u16*)(ws + OFF_N0L);
  u16* N2H = (u16*)(ws + OFF_N2H);
  u16* N2L = (u16*)(ws + OFF_N2L);

  hipLaunchKernelGGL(k_pcomb, dim3(256), dim3(1024), 0, stream, R_inv, pi_inv,
                     lengths, leaves, ws, PBH, PBL, LFH, LFL);
  hipLaunchKernelGGL(k_L0, dim3(512), dim3(256), 0, stream, LFH, LFL, PBH, PBL,
                     N0H, N0L);
  hipLaunchKernelGGL(k_L12, dim3(256), dim3(512), 0, stream, N0H, N0L, PBH,
                     PBL, N2H, N2L);
  hipLaunchKernelGGL(k_L34, dim3(128), dim3(512), 0, stream, N2H, N2L, PBH,
                     PBL, ws, out);
}